// Round 11
// baseline (457.799 us; speedup 1.0000x reference)
//
#include <hip/hip_runtime.h>
#include <hip/hip_bf16.h>
#include <stdint.h>

typedef __attribute__((ext_vector_type(8))) short short8;
typedef __attribute__((ext_vector_type(4))) short s16x4;
typedef __attribute__((ext_vector_type(4))) float f32x4;

#define GLDS16(gp, lp) __builtin_amdgcn_global_load_lds( \
    (const __attribute__((address_space(1))) void*)(gp), \
    (__attribute__((address_space(3))) void*)(lp), 16, 0, 0)

__device__ __forceinline__ unsigned short f2bf(float f) {
  union { float f; unsigned u; } v; v.f = f;
  unsigned r = v.u + 0x7FFFu + ((v.u >> 16) & 1u);
  return (unsigned short)(r >> 16);
}

__device__ __forceinline__ short bfpack(float f) {
  union { float f; unsigned u; } v; v.f = f;
  return (short)((v.u + 0x8000u) >> 16);
}

// ---------------- cast x (fp32 -> bf16), vectorized ----------------
__global__ __launch_bounds__(256) void cast_x(const float* __restrict__ x,
                                              unsigned short* __restrict__ o, int n4) {
  int i = blockIdx.x * 256 + threadIdx.x;
  if (i < n4) {
    float4 v = ((const float4*)x)[i];
    union { unsigned short u[4]; unsigned long long ll; } r;
    r.u[0] = f2bf(v.x); r.u[1] = f2bf(v.y); r.u[2] = f2bf(v.z); r.u[3] = f2bf(v.w);
    ((unsigned long long*)o)[i] = r.ll;
  }
}

// ------------- cast + transpose 4 weights in one launch -------------
__global__ __launch_bounds__(256) void cast_wt4(const float* __restrict__ W0,
                                                const float* __restrict__ W1,
                                                const float* __restrict__ W2,
                                                const float* __restrict__ W3,
                                                unsigned short* __restrict__ T0,
                                                unsigned short* __restrict__ T1,
                                                unsigned short* __restrict__ T2,
                                                unsigned short* __restrict__ T3) {
  __shared__ float t[16][17];
  const int z = blockIdx.z;
  const float* W = z == 0 ? W0 : (z == 1 ? W1 : (z == 2 ? W2 : W3));
  unsigned short* Wt = z == 0 ? T0 : (z == 1 ? T1 : (z == 2 ? T2 : T3));
  int tx = threadIdx.x, ty = threadIdx.y;
  int c0 = blockIdx.x * 16, r0 = blockIdx.y * 16;
  t[ty][tx] = W[(size_t)(r0 + ty) * 768 + c0 + tx];
  __syncthreads();
  Wt[(size_t)(c0 + ty) * 768 + r0 + tx] = f2bf(t[tx][ty]);
}

// ============ 256x256 QKV GEMM, 2-phase dbuf + counted vmcnt, 2 blocks/CU ============
// M=8192, N=2304, K=768, BK=32. 512 thr = 8 waves (2M x 4N), per-wave C = 128x64.
// LDS 64KB (2 dbuf x 16KB x {A,B}) -> 2 blocks/CU -> all 288 blocks co-resident
// (fixes round-10's 1-block/CU grid quantization). 2x arithmetic intensity per
// staged byte vs 128^2 (m112: 792 TF at this structure). Round-7 race-audited
// skeleton: vmcnt(4) -> barrier -> compute -> barrier -> restage freed buffer.
// Fragment mapping + epilogue identical to round-10's verified gemm_qkv8.
__global__ __launch_bounds__(512, 4) void gemm_qkv256(const unsigned short* __restrict__ A,
                                                      const unsigned short* __restrict__ Bt,
                                                      const float* __restrict__ bq,
                                                      const float* __restrict__ bk,
                                                      const float* __restrict__ bv,
                                                      unsigned short* __restrict__ Qb,
                                                      unsigned short* __restrict__ Kb,
                                                      unsigned short* __restrict__ Vt) {
  __shared__ unsigned short lA[2][8192];
  __shared__ unsigned short lB[2][8192];
  const int tid = threadIdx.x;
  const int l = tid & 63;
  const int wid = tid >> 6, wr = wid >> 2, wc = wid & 3;
  const int lr = l & 15, lk = l >> 4;
  const int rsw = (lr & 3) ^ (lr >> 2);
  // XCD-chunked bijective swizzle: 288 = 8 * 36
  const int bid = blockIdx.x;
  const int wgid = (bid & 7) * 36 + (bid >> 3);
  const int brow = wgid & 31, bcol = wgid >> 5;  // 32 x 9
  const int row0 = brow * 256, col0 = bcol * 256;
  // staging: A/B panel = 256x32 = 1024 16B-units; thread covers units tid, 512+tid
  const int r0s = tid >> 2;            // rows 0..127
  const int r1s = 128 + (tid >> 2);    // rows 128..255
  const int c0s = ((tid & 3) ^ (r0s & 3) ^ ((r0s >> 2) & 3)) * 8;
  const int c1s = ((tid & 3) ^ (r1s & 3) ^ ((r1s >> 2) & 3)) * 8;
  const unsigned short* Ar0 = A + (size_t)(row0 + r0s) * 768 + c0s;
  const unsigned short* Ar1 = A + (size_t)(row0 + r1s) * 768 + c1s;
  const unsigned short* Br0 = Bt + (size_t)(col0 + r0s) * 768 + c0s;
  const unsigned short* Br1 = Bt + (size_t)(col0 + r1s) * 768 + c1s;

#define GSTAGE(BUF, K0)                              \
  do {                                               \
    GLDS16(Ar0 + (K0), &lA[BUF][tid * 8]);           \
    GLDS16(Ar1 + (K0), &lA[BUF][(512 + tid) * 8]);   \
    GLDS16(Br0 + (K0), &lB[BUF][tid * 8]);           \
    GLDS16(Br1 + (K0), &lB[BUF][(512 + tid) * 8]);   \
  } while (0)

  f32x4 acc[8][4] = {};
  GSTAGE(0, 0);   // prologue: tiles 0,1 in flight (8 loads/wave... 8 instrs/thread)
  GSTAGE(1, 32);
#pragma unroll 1
  for (int kt = 0; kt < 24; ++kt) {
    if (kt < 23) {
      asm volatile("s_waitcnt vmcnt(4)" ::: "memory");  // stage(kt) landed
    } else {
      asm volatile("s_waitcnt vmcnt(0)" ::: "memory");
    }
    __builtin_amdgcn_s_barrier();
    __builtin_amdgcn_sched_barrier(0);
    const int cur = kt & 1;
    short8 af[8], bf[4];
#pragma unroll
    for (int i = 0; i < 8; ++i)
      af[i] = *(const short8*)(&lA[cur][(wr * 128 + i * 16 + lr) * 32 + (lk ^ rsw) * 8]);
#pragma unroll
    for (int j = 0; j < 4; ++j)
      bf[j] = *(const short8*)(&lB[cur][(wc * 64 + j * 16 + lr) * 32 + (lk ^ rsw) * 8]);
    __builtin_amdgcn_s_setprio(1);
#pragma unroll
    for (int i = 0; i < 8; ++i)
#pragma unroll
      for (int j = 0; j < 4; ++j)
        acc[i][j] = __builtin_amdgcn_mfma_f32_16x16x32_bf16(af[i], bf[j], acc[i][j], 0, 0, 0);
    __builtin_amdgcn_s_setprio(0);
    __builtin_amdgcn_sched_barrier(0);
    __builtin_amdgcn_s_barrier();                     // all waves done reading buf[cur]
    __builtin_amdgcn_sched_barrier(0);
    if (kt < 22) GSTAGE(cur, (kt + 2) * 32);          // refill freed buffer, 2 ahead
  }
#undef GSTAGE

  // ---- epilogue (identical mapping to round-10 verified gemm_qkv8) ----
  const int which = bcol / 3;  // 0:Q 1:K 2:V
  const int ncb = col0 - which * 768;
  if (which == 2) {
    const int mb = row0 + wr * 128;
    const int bb = mb >> 10;
    const int sbase = mb & 1023;
#pragma unroll
    for (int i = 0; i < 8; ++i) {
      const int sp = sbase + (i >> 1) * 32 + lk * 8 + (i & 1) * 4;
#pragma unroll
      for (int j = 0; j < 4; ++j) {
        const int n = ncb + wc * 64 + j * 16 + lr;
        const float bn = bv[n];
        s16x4 vv;
#pragma unroll
        for (int r = 0; r < 4; ++r) vv[r] = (short)f2bf(acc[i][j][r] + bn);
        *(s16x4*)(Vt + ((size_t)(bb * 768 + n)) * 1024 + sp) = vv;
      }
    }
  } else {
    unsigned short* outp = which == 0 ? Qb : Kb;
    const float* bias = which == 0 ? bq : bk;
    const float scale = which == 0 ? 0.18033688011112042f : 1.0f;  // 1/8 * log2(e)
#pragma unroll
    for (int i = 0; i < 8; ++i)
#pragma unroll
      for (int j = 0; j < 4; ++j) {
        const int n = ncb + wc * 64 + j * 16 + lr;
        const float bn = bias[n];
#pragma unroll
        for (int r = 0; r < 4; ++r) {
          const int m = row0 + wr * 128 + i * 16 + lk * 4 + r;
          outp[(size_t)m * 768 + n] = f2bf((acc[i][j][r] + bn) * scale);
        }
      }
  }
}

// ------------- 128x128 GEMM core (round-8 3-buf skeleton) — used by gemm_out -------------
__device__ __forceinline__ void gemm_core(const unsigned short* __restrict__ A,
                                          const unsigned short* __restrict__ Bt,
                                          int row0, int col0, f32x4 acc[4][4],
                                          unsigned short* sA, unsigned short* sB) {
  const int t = threadIdx.x, l = t & 63;
  const int w = t >> 6, wr = w >> 1, wc = w & 1;
  const int lr = l & 15, lk = l >> 4;
  const int rs = t >> 2;
  const int csw = ((t & 3) ^ (rs & 3) ^ ((t >> 4) & 3)) * 8;
  const int rsw = (lr & 3) ^ (lr >> 2);
  const unsigned short* Ar = A + (size_t)(row0 + rs) * 768 + csw;
  const unsigned short* Br = Bt + (size_t)(col0 + rs) * 768 + csw;

#define GSTAGE(BUF, K0)                                                     \
  do {                                                                      \
    GLDS16(Ar + (K0), sA + (BUF) * 4096 + t * 8);                           \
    GLDS16(Ar + (size_t)64 * 768 + (K0), sA + (BUF) * 4096 + 2048 + t * 8); \
    GLDS16(Br + (K0), sB + (BUF) * 4096 + t * 8);                           \
    GLDS16(Br + (size_t)64 * 768 + (K0), sB + (BUF) * 4096 + 2048 + t * 8); \
  } while (0)

#define GCOMPUTE(BUF)                                                            \
  do {                                                                           \
    const unsigned short* cA = sA + (BUF) * 4096;                                \
    const unsigned short* cB = sB + (BUF) * 4096;                                \
    short8 af[4], bfr[4];                                                        \
    _Pragma("unroll") for (int i = 0; i < 4; ++i)                                \
        af[i] = *(const short8*)(cA + (wr * 64 + i * 16 + lr) * 32 + ((lk ^ rsw) * 8)); \
    _Pragma("unroll") for (int i = 0; i < 4; ++i)                                \
        bfr[i] = *(const short8*)(cB + (wc * 64 + i * 16 + lr) * 32 + ((lk ^ rsw) * 8)); \
    __builtin_amdgcn_s_setprio(1);                                               \
    _Pragma("unroll") for (int i = 0; i < 4; ++i)                                \
        _Pragma("unroll") for (int j = 0; j < 4; ++j)                            \
            acc[i][j] = __builtin_amdgcn_mfma_f32_16x16x32_bf16(af[i], bfr[j], acc[i][j], 0, 0, 0); \
    __builtin_amdgcn_s_setprio(0);                                               \
  } while (0)

  GSTAGE(0, 0);
  GSTAGE(1, 32);
  int b0 = 0, b2 = 2;
#pragma unroll 1
  for (int kt = 0; kt < 23; ++kt) {
    asm volatile("s_waitcnt vmcnt(4)" ::: "memory");
    __builtin_amdgcn_s_barrier();
    __builtin_amdgcn_sched_barrier(0);
    if (kt < 22) GSTAGE(b2, (kt + 2) * 32);
    GCOMPUTE(b0);
    b0 = (b0 == 2) ? 0 : b0 + 1;
    b2 = (b2 == 2) ? 0 : b2 + 1;
  }
  asm volatile("s_waitcnt vmcnt(0)" ::: "memory");
  __builtin_amdgcn_s_barrier();
  __builtin_amdgcn_sched_barrier(0);
  GCOMPUTE(b0);
#undef GSTAGE
#undef GCOMPUTE
}

// ------------- output projection: M=8192, N=768, K=768, f32 out -------------
__global__ __launch_bounds__(256, 3) void gemm_out(const unsigned short* __restrict__ A,
                                                   const unsigned short* __restrict__ Bt,
                                                   const float* __restrict__ bias,
                                                   float* __restrict__ C) {
  __shared__ unsigned short sA[3][4096];
  __shared__ unsigned short sB[3][4096];
  const int flat = blockIdx.x;
  const int xcd = flat & 7, idx = flat >> 3;
  const int brow = xcd * 8 + (idx & 7);
  const int bcol = idx >> 3;
  const int row0 = brow * 128, col0 = bcol * 128;
  f32x4 acc[4][4] = {};
  gemm_core(A, Bt, row0, col0, acc, &sA[0][0], &sB[0][0]);

  const int l = threadIdx.x & 63, w = threadIdx.x >> 6;
  const int wr = w >> 1, wc = w & 1, lr = l & 15, lk = l >> 4;
#pragma unroll
  for (int i = 0; i < 4; ++i)
#pragma unroll
    for (int j = 0; j < 4; ++j) {
      int n = col0 + wc * 64 + j * 16 + lr;
      float bn = bias[n];
#pragma unroll
      for (int r = 0; r < 4; ++r) {
        int m = row0 + wr * 64 + i * 16 + lk * 4 + r;
        C[(size_t)m * 768 + n] = acc[i][j][r] + bn;
      }
    }
}

// ------------- causal flash attention (round-8/9, unchanged) -------------
__global__ __launch_bounds__(256, 3) void attn(const unsigned short* __restrict__ Q,
                                               const unsigned short* __restrict__ Kg,
                                               const unsigned short* __restrict__ V2,
                                               unsigned short* __restrict__ O) {
  __shared__ unsigned short Kl[3][4096];
  __shared__ unsigned short Vl[3][4096];
  const int tid = threadIdx.x;
  const int l = tid & 63, w = tid >> 6;
  const int lr = l & 15, lk = l >> 4;
  const int o = blockIdx.x;
  const int b = o & 7, rem = o >> 3, pair = rem & 7, h = rem >> 3;
  const int hd = h * 64;
  const size_t bS = (size_t)b * 1024;
  const unsigned short* Kbase = Kg + bS * 768 + hd;
  const unsigned short* Vbase = V2 + ((size_t)b * 768 + hd) * 1024;
  const int rs = tid >> 3;
  const int kcol = ((tid & 7) ^ (rs & 7)) * 8;
  const int swz = (lr & 7);
  const int qloc = w * 16 + lr;

#define STAGE(BUF, T)                                                          \
  do {                                                                         \
    const size_t kv0_ = (size_t)(T) * 64;                                      \
    GLDS16(Kbase + (kv0_ + rs) * 768 + kcol, &Kl[BUF][tid * 8]);               \
    GLDS16(Kbase + (kv0_ + rs + 32) * 768 + kcol, &Kl[BUF][(256 + tid) * 8]);  \
    GLDS16(Vbase + (size_t)rs * 1024 + kv0_ + kcol, &Vl[BUF][tid * 8]);        \
    GLDS16(Vbase + (size_t)(rs + 32) * 1024 + kv0_ + kcol,                     \
           &Vl[BUF][(256 + tid) * 8]);                                         \
  } while (0)

#pragma unroll 1
  for (int half = 0; half < 2; ++half) {
    const int qt = half ? 15 - pair : pair;
    const int qw = qt * 64 + w * 16;
    const int ntile = qt + 1;
    __syncthreads();
    short8 bq0, bq1;
    {
      size_t qb = (bS + qw + lr) * 768 + hd + lk * 8;
      bq0 = *(const short8*)(Q + qb);
      bq1 = *(const short8*)(Q + qb + 32);
    }
    f32x4 oc0 = {}, oc1 = {}, oc2 = {}, oc3 = {};
    float lsum = 0.f;

    STAGE(0, 0);
    if (ntile > 1) STAGE(1, 1);
    int b0 = 0, b2 = 2;

#pragma unroll 1
    for (int t = 0; t < ntile; ++t) {
      if (t < ntile - 1) {
        asm volatile("s_waitcnt vmcnt(4)" ::: "memory");
      } else {
        asm volatile("s_waitcnt vmcnt(0)" ::: "memory");
      }
      __builtin_amdgcn_s_barrier();
      __builtin_amdgcn_sched_barrier(0);
      if (t + 2 < ntile) STAGE(b2, t + 2);
      const unsigned short* Kb_ = Kl[b0];
      const unsigned short* Vb_ = Vl[b0];
      b0 = (b0 == 2) ? 0 : b0 + 1;
      b2 = (b2 == 2) ? 0 : b2 + 1;
      short8 kf00 = *(const short8*)(Kb_ + (0 * 16 + lr) * 64 + (((0 * 4 + lk) ^ swz) * 8));
      short8 kf01 = *(const short8*)(Kb_ + (0 * 16 + lr) * 64 + (((1 * 4 + lk) ^ swz) * 8));
      short8 kf10 = *(const short8*)(Kb_ + (1 * 16 + lr) * 64 + (((0 * 4 + lk) ^ swz) * 8));
      short8 kf11 = *(const short8*)(Kb_ + (1 * 16 + lr) * 64 + (((1 * 4 + lk) ^ swz) * 8));
      short8 kf20 = *(const short8*)(Kb_ + (2 * 16 + lr) * 64 + (((0 * 4 + lk) ^ swz) * 8));
      short8 kf21 = *(const short8*)(Kb_ + (2 * 16 + lr) * 64 + (((1 * 4 + lk) ^ swz) * 8));
      short8 kf30 = *(const short8*)(Kb_ + (3 * 16 + lr) * 64 + (((0 * 4 + lk) ^ swz) * 8));
      short8 kf31 = *(const short8*)(Kb_ + (3 * 16 + lr) * 64 + (((1 * 4 + lk) ^ swz) * 8));
      short8 vf00 = *(const short8*)(Vb_ + (0 * 16 + lr) * 64 + (((0 * 4 + lk) ^ swz) * 8));
      short8 vf01 = *(const short8*)(Vb_ + (0 * 16 + lr) * 64 + (((1 * 4 + lk) ^ swz) * 8));
      short8 vf10 = *(const short8*)(Vb_ + (1 * 16 + lr) * 64 + (((0 * 4 + lk) ^ swz) * 8));
      short8 vf11 = *(const short8*)(Vb_ + (1 * 16 + lr) * 64 + (((1 * 4 + lk) ^ swz) * 8));
      short8 vf20 = *(const short8*)(Vb_ + (2 * 16 + lr) * 64 + (((0 * 4 + lk) ^ swz) * 8));
      short8 vf21 = *(const short8*)(Vb_ + (2 * 16 + lr) * 64 + (((1 * 4 + lk) ^ swz) * 8));
      short8 vf30 = *(const short8*)(Vb_ + (3 * 16 + lr) * 64 + (((0 * 4 + lk) ^ swz) * 8));
      short8 vf31 = *(const short8*)(Vb_ + (3 * 16 + lr) * 64 + (((1 * 4 + lk) ^ swz) * 8));

      f32x4 s0 = {}, s1 = {}, s2 = {}, s3 = {};
      __builtin_amdgcn_s_setprio(1);
      s0 = __builtin_amdgcn_mfma_f32_16x16x32_bf16(kf00, bq0, s0, 0, 0, 0);
      s0 = __builtin_amdgcn_mfma_f32_16x16x32_bf16(kf01, bq1, s0, 0, 0, 0);
      s1 = __builtin_amdgcn_mfma_f32_16x16x32_bf16(kf10, bq0, s1, 0, 0, 0);
      s1 = __builtin_amdgcn_mfma_f32_16x16x32_bf16(kf11, bq1, s1, 0, 0, 0);
      s2 = __builtin_amdgcn_mfma_f32_16x16x32_bf16(kf20, bq0, s2, 0, 0, 0);
      s2 = __builtin_amdgcn_mfma_f32_16x16x32_bf16(kf21, bq1, s2, 0, 0, 0);
      s3 = __builtin_amdgcn_mfma_f32_16x16x32_bf16(kf30, bq0, s3, 0, 0, 0);
      s3 = __builtin_amdgcn_mfma_f32_16x16x32_bf16(kf31, bq1, s3, 0, 0, 0);
      __builtin_amdgcn_s_setprio(0);

      if (t == ntile - 1) {
        const int kb = lk * 4;
#pragma unroll
        for (int r = 0; r < 4; ++r) {
          if (kb + 0 + r > qloc) s0[r] = -1e30f;
          if (kb + 16 + r > qloc) s1[r] = -1e30f;
          if (kb + 32 + r > qloc) s2[r] = -1e30f;
          if (kb + 48 + r > qloc) s3[r] = -1e30f;
        }
      }
      float p0[4], p1[4], p2[4], p3[4];
#pragma unroll
      for (int r = 0; r < 4; ++r) {
        p0[r] = __builtin_amdgcn_exp2f(s0[r]);
        p1[r] = __builtin_amdgcn_exp2f(s1[r]);
        p2[r] = __builtin_amdgcn_exp2f(s2[r]);
        p3[r] = __builtin_amdgcn_exp2f(s3[r]);
      }
      lsum += ((p0[0] + p0[1]) + (p0[2] + p0[3])) + ((p1[0] + p1[1]) + (p1[2] + p1[3])) +
              ((p2[0] + p2[1]) + (p2[2] + p2[3])) + ((p3[0] + p3[1]) + (p3[2] + p3[3]));
      short8 pb0, pb1;
#pragma unroll
      for (int r = 0; r < 4; ++r) {
        pb0[r] = bfpack(p0[r]); pb0[r + 4] = bfpack(p1[r]);
        pb1[r] = bfpack(p2[r]); pb1[r + 4] = bfpack(p3[r]);
      }
      __builtin_amdgcn_s_setprio(1);
      oc0 = __builtin_amdgcn_mfma_f32_16x16x32_bf16(vf00, pb0, oc0, 0, 0, 0);
      oc0 = __builtin_amdgcn_mfma_f32_16x16x32_bf16(vf01, pb1, oc0, 0, 0, 0);
      oc1 = __builtin_amdgcn_mfma_f32_16x16x32_bf16(vf10, pb0, oc1, 0, 0, 0);
      oc1 = __builtin_amdgcn_mfma_f32_16x16x32_bf16(vf11, pb1, oc1, 0, 0, 0);
      oc2 = __builtin_amdgcn_mfma_f32_16x16x32_bf16(vf20, pb0, oc2, 0, 0, 0);
      oc2 = __builtin_amdgcn_mfma_f32_16x16x32_bf16(vf21, pb1, oc2, 0, 0, 0);
      oc3 = __builtin_amdgcn_mfma_f32_16x16x32_bf16(vf30, pb0, oc3, 0, 0, 0);
      oc3 = __builtin_amdgcn_mfma_f32_16x16x32_bf16(vf31, pb1, oc3, 0, 0, 0);
      __builtin_amdgcn_s_setprio(0);
    }

    lsum += __shfl_xor(lsum, 16);
    lsum += __shfl_xor(lsum, 32);
    const float inv = 1.f / lsum;
    unsigned short* op = O + (bS + qw + lr) * 768 + hd + lk * 4;
    s16x4 o0, o1, o2, o3;
#pragma unroll
    for (int r = 0; r < 4; ++r) {
      o0[r] = (short)f2bf(oc0[r] * inv);
      o1[r] = (short)f2bf(oc1[r] * inv);
      o2[r] = (short)f2bf(oc2[r] * inv);
      o3[r] = (short)f2bf(oc3[r] * inv);
    }
    *(s16x4*)(op) = o0;
    *(s16x4*)(op + 16) = o1;
    *(s16x4*)(op + 32) = o2;
    *(s16x4*)(op + 48) = o3;
  }
#undef STAGE
}

extern "C" void kernel_launch(void* const* d_in, const int* in_sizes, int n_in,
                              void* d_out, int out_size, void* d_ws, size_t ws_size,
                              hipStream_t stream) {
  const float* x  = (const float*)d_in[0];
  const float* Wq = (const float*)d_in[2]; const float* bq = (const float*)d_in[3];
  const float* Wk = (const float*)d_in[4]; const float* bk = (const float*)d_in[5];
  const float* Wv = (const float*)d_in[6]; const float* bv = (const float*)d_in[7];
  const float* Wo = (const float*)d_in[8]; const float* bo = (const float*)d_in[9];
  float* out = (float*)d_out;

  char* ws = (char*)d_ws;
  unsigned short* xb  = (unsigned short*)ws;
  unsigned short* WtQ = (unsigned short*)(ws + (size_t)12582912);
  unsigned short* WtK = WtQ + 589824;
  unsigned short* WtV = WtK + 589824;
  unsigned short* WtO = WtV + 589824;
  unsigned short* Qb  = (unsigned short*)(ws + (size_t)12582912 + (size_t)4 * 1179648);
  unsigned short* Kb  = Qb + 6291456;
  unsigned short* Vt  = Kb + 2 * 6291456;
  unsigned short* Ob  = xb;  // xb dead after QKV projection

  cast_x<<<6144, 256, 0, stream>>>(x, xb, 1572864);
  cast_wt4<<<dim3(48, 48, 4), dim3(16, 16), 0, stream>>>(Wq, Wk, Wv, Wo, WtQ, WtK, WtV, WtO);
  gemm_qkv256<<<288, 512, 0, stream>>>(xb, WtQ, bq, bk, bv, Qb, Kb, Vt);
  attn<<<768, 256, 0, stream>>>(Qb, Kb, Vt, Ob);
  gemm_out<<<384, 256, 0, stream>>>(Ob, WtO, bo, out);
}

// Round 12
// 105.499 us; speedup vs baseline: 4.3394x; 4.3394x over previous
//
#include <hip/hip_runtime.h>
#include <hip/hip_bf16.h>
#include <stdint.h>

typedef __attribute__((ext_vector_type(8))) short short8;
typedef __attribute__((ext_vector_type(4))) short s16x4;
typedef __attribute__((ext_vector_type(4))) float f32x4;

#define GLDS16(gp, lp) __builtin_amdgcn_global_load_lds( \
    (const __attribute__((address_space(1))) void*)(gp), \
    (__attribute__((address_space(3))) void*)(lp), 16, 0, 0)

__device__ __forceinline__ unsigned short f2bf(float f) {
  union { float f; unsigned u; } v; v.f = f;
  unsigned r = v.u + 0x7FFFu + ((v.u >> 16) & 1u);
  return (unsigned short)(r >> 16);
}

__device__ __forceinline__ short bfpack(float f) {
  union { float f; unsigned u; } v; v.f = f;
  return (short)((v.u + 0x8000u) >> 16);
}

// ---------------- cast x (fp32 -> bf16), vectorized ----------------
__global__ __launch_bounds__(256) void cast_x(const float* __restrict__ x,
                                              unsigned short* __restrict__ o, int n4) {
  int i = blockIdx.x * 256 + threadIdx.x;
  if (i < n4) {
    float4 v = ((const float4*)x)[i];
    union { unsigned short u[4]; unsigned long long ll; } r;
    r.u[0] = f2bf(v.x); r.u[1] = f2bf(v.y); r.u[2] = f2bf(v.z); r.u[3] = f2bf(v.w);
    ((unsigned long long*)o)[i] = r.ll;
  }
}

// ------------- cast + transpose 4 weights in one launch -------------
__global__ __launch_bounds__(256) void cast_wt4(const float* __restrict__ W0,
                                                const float* __restrict__ W1,
                                                const float* __restrict__ W2,
                                                const float* __restrict__ W3,
                                                unsigned short* __restrict__ T0,
                                                unsigned short* __restrict__ T1,
                                                unsigned short* __restrict__ T2,
                                                unsigned short* __restrict__ T3) {
  __shared__ float t[16][17];
  const int z = blockIdx.z;
  const float* W = z == 0 ? W0 : (z == 1 ? W1 : (z == 2 ? W2 : W3));
  unsigned short* Wt = z == 0 ? T0 : (z == 1 ? T1 : (z == 2 ? T2 : T3));
  int tx = threadIdx.x, ty = threadIdx.y;
  int c0 = blockIdx.x * 16, r0 = blockIdx.y * 16;
  t[ty][tx] = W[(size_t)(r0 + ty) * 768 + c0 + tx];
  __syncthreads();
  Wt[(size_t)(c0 + ty) * 768 + r0 + tx] = f2bf(t[tx][ty]);
}

// ------------- shared GEMM mainloop: C[128x128] += A[128xK] * Bt[128xK]^T, K=768 -------------
// Round-9 proven structure: triple-buffer, ONE barrier per K-step, depth-2 counted
// vmcnt. 256^2-tile alternatives are structurally blocked on this shape:
// 8-phase (128KB LDS -> 1 blk/CU, grid 288>256 quantization, r10) and 2-phase
// (acc=128 VGPR/lane -> spills under any >1 blk/CU launch_bounds, r11).
__device__ __forceinline__ void gemm_core(const unsigned short* __restrict__ A,
                                          const unsigned short* __restrict__ Bt,
                                          int row0, int col0, f32x4 acc[4][4],
                                          unsigned short* sA, unsigned short* sB) {
  const int t = threadIdx.x, l = t & 63;
  const int w = t >> 6, wr = w >> 1, wc = w & 1;
  const int lr = l & 15, lk = l >> 4;
  const int rs = t >> 2;
  const int csw = ((t & 3) ^ (rs & 3) ^ ((t >> 4) & 3)) * 8;
  const int rsw = (lr & 3) ^ (lr >> 2);
  const unsigned short* Ar = A + (size_t)(row0 + rs) * 768 + csw;
  const unsigned short* Br = Bt + (size_t)(col0 + rs) * 768 + csw;

#define GSTAGE(BUF, K0)                                                     \
  do {                                                                      \
    GLDS16(Ar + (K0), sA + (BUF) * 4096 + t * 8);                           \
    GLDS16(Ar + (size_t)64 * 768 + (K0), sA + (BUF) * 4096 + 2048 + t * 8); \
    GLDS16(Br + (K0), sB + (BUF) * 4096 + t * 8);                           \
    GLDS16(Br + (size_t)64 * 768 + (K0), sB + (BUF) * 4096 + 2048 + t * 8); \
  } while (0)

#define GCOMPUTE(BUF)                                                            \
  do {                                                                           \
    const unsigned short* cA = sA + (BUF) * 4096;                                \
    const unsigned short* cB = sB + (BUF) * 4096;                                \
    short8 af[4], bfr[4];                                                        \
    _Pragma("unroll") for (int i = 0; i < 4; ++i)                                \
        af[i] = *(const short8*)(cA + (wr * 64 + i * 16 + lr) * 32 + ((lk ^ rsw) * 8)); \
    _Pragma("unroll") for (int i = 0; i < 4; ++i)                                \
        bfr[i] = *(const short8*)(cB + (wc * 64 + i * 16 + lr) * 32 + ((lk ^ rsw) * 8)); \
    __builtin_amdgcn_s_setprio(1);                                               \
    _Pragma("unroll") for (int i = 0; i < 4; ++i)                                \
        _Pragma("unroll") for (int j = 0; j < 4; ++j)                            \
            acc[i][j] = __builtin_amdgcn_mfma_f32_16x16x32_bf16(af[i], bfr[j], acc[i][j], 0, 0, 0); \
    __builtin_amdgcn_s_setprio(0);                                               \
  } while (0)

  GSTAGE(0, 0);
  GSTAGE(1, 32);
  int b0 = 0, b2 = 2;
#pragma unroll 1
  for (int kt = 0; kt < 23; ++kt) {
    asm volatile("s_waitcnt vmcnt(4)" ::: "memory");
    __builtin_amdgcn_s_barrier();
    __builtin_amdgcn_sched_barrier(0);
    if (kt < 22) GSTAGE(b2, (kt + 2) * 32);
    GCOMPUTE(b0);
    b0 = (b0 == 2) ? 0 : b0 + 1;
    b2 = (b2 == 2) ? 0 : b2 + 1;
  }
  asm volatile("s_waitcnt vmcnt(0)" ::: "memory");
  __builtin_amdgcn_s_barrier();
  __builtin_amdgcn_sched_barrier(0);
  GCOMPUTE(b0);
#undef GSTAGE
#undef GCOMPUTE
}

// ------------- fused QKV projection: M=8192, N=2304 (Q|K|V), K=768, bf16 out -------------
__global__ __launch_bounds__(256, 3) void gemm_qkv(const unsigned short* __restrict__ A,
                                                   const unsigned short* __restrict__ Bt,
                                                   const float* __restrict__ bq,
                                                   const float* __restrict__ bk,
                                                   const float* __restrict__ bv,
                                                   unsigned short* __restrict__ Qb,
                                                   unsigned short* __restrict__ Kb,
                                                   unsigned short* __restrict__ Vt) {
  __shared__ unsigned short sA[3][4096];
  __shared__ unsigned short sB[3][4096];
  const int flat = blockIdx.x;
  const int xcd = flat & 7, idx = flat >> 3;
  const int brow = xcd * 8 + (idx & 7);   // 0..63
  const int bcol = idx >> 3;              // 0..17
  const int row0 = brow * 128, col0 = bcol * 128;
  f32x4 acc[4][4] = {};
  gemm_core(A, Bt, row0, col0, acc, &sA[0][0], &sB[0][0]);

  const int l = threadIdx.x & 63, w = threadIdx.x >> 6;
  const int wr = w >> 1, wc = w & 1, lr = l & 15, lk = l >> 4;
  const int which = bcol / 6;             // uniform per block
  const int ncb = col0 - which * 768;
  if (which == 2) {
    const int bb = row0 >> 10;
    const int sb = (row0 & 1023) + wr * 64;
#pragma unroll
    for (int i = 0; i < 4; ++i) {
      const int sp = sb + (i >> 1) * 32 + lk * 8 + (i & 1) * 4;
#pragma unroll
      for (int j = 0; j < 4; ++j) {
        const int n = ncb + wc * 64 + j * 16 + lr;
        const float bn = bv[n];
        s16x4 vv;
#pragma unroll
        for (int r = 0; r < 4; ++r) vv[r] = (short)f2bf(acc[i][j][r] + bn);
        *(s16x4*)(Vt + ((size_t)(bb * 768 + n)) * 1024 + sp) = vv;
      }
    }
  } else {
    unsigned short* outp = which == 0 ? Qb : Kb;
    const float* bias = which == 0 ? bq : bk;
    const float scale = which == 0 ? 0.18033688011112042f : 1.0f;  // 1/8 * log2(e)
#pragma unroll
    for (int i = 0; i < 4; ++i)
#pragma unroll
      for (int j = 0; j < 4; ++j) {
        int n = ncb + wc * 64 + j * 16 + lr;
        float bn = bias[n];
#pragma unroll
        for (int r = 0; r < 4; ++r) {
          int m = row0 + wr * 64 + i * 16 + lk * 4 + r;
          outp[(size_t)m * 768 + n] = f2bf((acc[i][j][r] + bn) * scale);
        }
      }
  }
}

// ------------- output projection: M=8192, N=768, K=768, f32 out -------------
__global__ __launch_bounds__(256, 3) void gemm_out(const unsigned short* __restrict__ A,
                                                   const unsigned short* __restrict__ Bt,
                                                   const float* __restrict__ bias,
                                                   float* __restrict__ C) {
  __shared__ unsigned short sA[3][4096];
  __shared__ unsigned short sB[3][4096];
  const int flat = blockIdx.x;
  const int xcd = flat & 7, idx = flat >> 3;
  const int brow = xcd * 8 + (idx & 7);
  const int bcol = idx >> 3;
  const int row0 = brow * 128, col0 = bcol * 128;
  f32x4 acc[4][4] = {};
  gemm_core(A, Bt, row0, col0, acc, &sA[0][0], &sB[0][0]);

  const int l = threadIdx.x & 63, w = threadIdx.x >> 6;
  const int wr = w >> 1, wc = w & 1, lr = l & 15, lk = l >> 4;
#pragma unroll
  for (int i = 0; i < 4; ++i)
#pragma unroll
    for (int j = 0; j < 4; ++j) {
      int n = col0 + wc * 64 + j * 16 + lr;
      float bn = bias[n];
#pragma unroll
      for (int r = 0; r < 4; ++r) {
        int m = row0 + wr * 64 + i * 16 + lk * 4 + r;
        C[(size_t)m * 768 + n] = acc[i][j][r] + bn;
      }
    }
}

// ------------- causal flash attention, block-cooperative LDS, 3-buf 1-barrier -------------
__global__ __launch_bounds__(256, 3) void attn(const unsigned short* __restrict__ Q,
                                               const unsigned short* __restrict__ Kg,
                                               const unsigned short* __restrict__ V2,
                                               unsigned short* __restrict__ O) {
  __shared__ unsigned short Kl[3][4096];
  __shared__ unsigned short Vl[3][4096];
  const int tid = threadIdx.x;
  const int l = tid & 63, w = tid >> 6;
  const int lr = l & 15, lk = l >> 4;
  const int o = blockIdx.x;
  const int b = o & 7, rem = o >> 3, pair = rem & 7, h = rem >> 3;
  const int hd = h * 64;
  const size_t bS = (size_t)b * 1024;
  const unsigned short* Kbase = Kg + bS * 768 + hd;
  const unsigned short* Vbase = V2 + ((size_t)b * 768 + hd) * 1024;
  const int rs = tid >> 3;
  const int kcol = ((tid & 7) ^ (rs & 7)) * 8;
  const int swz = (lr & 7);
  const int qloc = w * 16 + lr;

#define STAGE(BUF, T)                                                          \
  do {                                                                         \
    const size_t kv0_ = (size_t)(T) * 64;                                      \
    GLDS16(Kbase + (kv0_ + rs) * 768 + kcol, &Kl[BUF][tid * 8]);               \
    GLDS16(Kbase + (kv0_ + rs + 32) * 768 + kcol, &Kl[BUF][(256 + tid) * 8]);  \
    GLDS16(Vbase + (size_t)rs * 1024 + kv0_ + kcol, &Vl[BUF][tid * 8]);        \
    GLDS16(Vbase + (size_t)(rs + 32) * 1024 + kv0_ + kcol,                     \
           &Vl[BUF][(256 + tid) * 8]);                                         \
  } while (0)

#pragma unroll 1
  for (int half = 0; half < 2; ++half) {
    const int qt = half ? 15 - pair : pair;
    const int qw = qt * 64 + w * 16;
    const int ntile = qt + 1;
    __syncthreads();
    short8 bq0, bq1;
    {
      size_t qb = (bS + qw + lr) * 768 + hd + lk * 8;
      bq0 = *(const short8*)(Q + qb);
      bq1 = *(const short8*)(Q + qb + 32);
    }
    f32x4 oc0 = {}, oc1 = {}, oc2 = {}, oc3 = {};
    float lsum = 0.f;

    STAGE(0, 0);
    if (ntile > 1) STAGE(1, 1);
    int b0 = 0, b2 = 2;

#pragma unroll 1
    for (int t = 0; t < ntile; ++t) {
      if (t < ntile - 1) {
        asm volatile("s_waitcnt vmcnt(4)" ::: "memory");
      } else {
        asm volatile("s_waitcnt vmcnt(0)" ::: "memory");
      }
      __builtin_amdgcn_s_barrier();
      __builtin_amdgcn_sched_barrier(0);
      if (t + 2 < ntile) STAGE(b2, t + 2);
      const unsigned short* Kb_ = Kl[b0];
      const unsigned short* Vb_ = Vl[b0];
      b0 = (b0 == 2) ? 0 : b0 + 1;
      b2 = (b2 == 2) ? 0 : b2 + 1;
      short8 kf00 = *(const short8*)(Kb_ + (0 * 16 + lr) * 64 + (((0 * 4 + lk) ^ swz) * 8));
      short8 kf01 = *(const short8*)(Kb_ + (0 * 16 + lr) * 64 + (((1 * 4 + lk) ^ swz) * 8));
      short8 kf10 = *(const short8*)(Kb_ + (1 * 16 + lr) * 64 + (((0 * 4 + lk) ^ swz) * 8));
      short8 kf11 = *(const short8*)(Kb_ + (1 * 16 + lr) * 64 + (((1 * 4 + lk) ^ swz) * 8));
      short8 kf20 = *(const short8*)(Kb_ + (2 * 16 + lr) * 64 + (((0 * 4 + lk) ^ swz) * 8));
      short8 kf21 = *(const short8*)(Kb_ + (2 * 16 + lr) * 64 + (((1 * 4 + lk) ^ swz) * 8));
      short8 kf30 = *(const short8*)(Kb_ + (3 * 16 + lr) * 64 + (((0 * 4 + lk) ^ swz) * 8));
      short8 kf31 = *(const short8*)(Kb_ + (3 * 16 + lr) * 64 + (((1 * 4 + lk) ^ swz) * 8));
      short8 vf00 = *(const short8*)(Vb_ + (0 * 16 + lr) * 64 + (((0 * 4 + lk) ^ swz) * 8));
      short8 vf01 = *(const short8*)(Vb_ + (0 * 16 + lr) * 64 + (((1 * 4 + lk) ^ swz) * 8));
      short8 vf10 = *(const short8*)(Vb_ + (1 * 16 + lr) * 64 + (((0 * 4 + lk) ^ swz) * 8));
      short8 vf11 = *(const short8*)(Vb_ + (1 * 16 + lr) * 64 + (((1 * 4 + lk) ^ swz) * 8));
      short8 vf20 = *(const short8*)(Vb_ + (2 * 16 + lr) * 64 + (((0 * 4 + lk) ^ swz) * 8));
      short8 vf21 = *(const short8*)(Vb_ + (2 * 16 + lr) * 64 + (((1 * 4 + lk) ^ swz) * 8));
      short8 vf30 = *(const short8*)(Vb_ + (3 * 16 + lr) * 64 + (((0 * 4 + lk) ^ swz) * 8));
      short8 vf31 = *(const short8*)(Vb_ + (3 * 16 + lr) * 64 + (((1 * 4 + lk) ^ swz) * 8));

      f32x4 s0 = {}, s1 = {}, s2 = {}, s3 = {};
      __builtin_amdgcn_s_setprio(1);
      s0 = __builtin_amdgcn_mfma_f32_16x16x32_bf16(kf00, bq0, s0, 0, 0, 0);
      s0 = __builtin_amdgcn_mfma_f32_16x16x32_bf16(kf01, bq1, s0, 0, 0, 0);
      s1 = __builtin_amdgcn_mfma_f32_16x16x32_bf16(kf10, bq0, s1, 0, 0, 0);
      s1 = __builtin_amdgcn_mfma_f32_16x16x32_bf16(kf11, bq1, s1, 0, 0, 0);
      s2 = __builtin_amdgcn_mfma_f32_16x16x32_bf16(kf20, bq0, s2, 0, 0, 0);
      s2 = __builtin_amdgcn_mfma_f32_16x16x32_bf16(kf21, bq1, s2, 0, 0, 0);
      s3 = __builtin_amdgcn_mfma_f32_16x16x32_bf16(kf30, bq0, s3, 0, 0, 0);
      s3 = __builtin_amdgcn_mfma_f32_16x16x32_bf16(kf31, bq1, s3, 0, 0, 0);
      __builtin_amdgcn_s_setprio(0);

      if (t == ntile - 1) {
        const int kb = lk * 4;
#pragma unroll
        for (int r = 0; r < 4; ++r) {
          if (kb + 0 + r > qloc) s0[r] = -1e30f;
          if (kb + 16 + r > qloc) s1[r] = -1e30f;
          if (kb + 32 + r > qloc) s2[r] = -1e30f;
          if (kb + 48 + r > qloc) s3[r] = -1e30f;
        }
      }
      float p0[4], p1[4], p2[4], p3[4];
#pragma unroll
      for (int r = 0; r < 4; ++r) {
        p0[r] = __builtin_amdgcn_exp2f(s0[r]);
        p1[r] = __builtin_amdgcn_exp2f(s1[r]);
        p2[r] = __builtin_amdgcn_exp2f(s2[r]);
        p3[r] = __builtin_amdgcn_exp2f(s3[r]);
      }
      lsum += ((p0[0] + p0[1]) + (p0[2] + p0[3])) + ((p1[0] + p1[1]) + (p1[2] + p1[3])) +
              ((p2[0] + p2[1]) + (p2[2] + p2[3])) + ((p3[0] + p3[1]) + (p3[2] + p3[3]));
      short8 pb0, pb1;
#pragma unroll
      for (int r = 0; r < 4; ++r) {
        pb0[r] = bfpack(p0[r]); pb0[r + 4] = bfpack(p1[r]);
        pb1[r] = bfpack(p2[r]); pb1[r + 4] = bfpack(p3[r]);
      }
      __builtin_amdgcn_s_setprio(1);
      oc0 = __builtin_amdgcn_mfma_f32_16x16x32_bf16(vf00, pb0, oc0, 0, 0, 0);
      oc0 = __builtin_amdgcn_mfma_f32_16x16x32_bf16(vf01, pb1, oc0, 0, 0, 0);
      oc1 = __builtin_amdgcn_mfma_f32_16x16x32_bf16(vf10, pb0, oc1, 0, 0, 0);
      oc1 = __builtin_amdgcn_mfma_f32_16x16x32_bf16(vf11, pb1, oc1, 0, 0, 0);
      oc2 = __builtin_amdgcn_mfma_f32_16x16x32_bf16(vf20, pb0, oc2, 0, 0, 0);
      oc2 = __builtin_amdgcn_mfma_f32_16x16x32_bf16(vf21, pb1, oc2, 0, 0, 0);
      oc3 = __builtin_amdgcn_mfma_f32_16x16x32_bf16(vf30, pb0, oc3, 0, 0, 0);
      oc3 = __builtin_amdgcn_mfma_f32_16x16x32_bf16(vf31, pb1, oc3, 0, 0, 0);
      __builtin_amdgcn_s_setprio(0);
    }

    lsum += __shfl_xor(lsum, 16);
    lsum += __shfl_xor(lsum, 32);
    const float inv = 1.f / lsum;
    unsigned short* op = O + (bS + qw + lr) * 768 + hd + lk * 4;
    s16x4 o0, o1, o2, o3;
#pragma unroll
    for (int r = 0; r < 4; ++r) {
      o0[r] = (short)f2bf(oc0[r] * inv);
      o1[r] = (short)f2bf(oc1[r] * inv);
      o2[r] = (short)f2bf(oc2[r] * inv);
      o3[r] = (short)f2bf(oc3[r] * inv);
    }
    *(s16x4*)(op) = o0;
    *(s16x4*)(op + 16) = o1;
    *(s16x4*)(op + 32) = o2;
    *(s16x4*)(op + 48) = o3;
  }
#undef STAGE
}

extern "C" void kernel_launch(void* const* d_in, const int* in_sizes, int n_in,
                              void* d_out, int out_size, void* d_ws, size_t ws_size,
                              hipStream_t stream) {
  const float* x  = (const float*)d_in[0];
  const float* Wq = (const float*)d_in[2]; const float* bq = (const float*)d_in[3];
  const float* Wk = (const float*)d_in[4]; const float* bk = (const float*)d_in[5];
  const float* Wv = (const float*)d_in[6]; const float* bv = (const float*)d_in[7];
  const float* Wo = (const float*)d_in[8]; const float* bo = (const float*)d_in[9];
  float* out = (float*)d_out;

  char* ws = (char*)d_ws;
  unsigned short* xb  = (unsigned short*)ws;
  unsigned short* WtQ = (unsigned short*)(ws + (size_t)12582912);
  unsigned short* WtK = WtQ + 589824;
  unsigned short* WtV = WtK + 589824;
  unsigned short* WtO = WtV + 589824;
  unsigned short* Qb  = (unsigned short*)(ws + (size_t)12582912 + (size_t)4 * 1179648);
  unsigned short* Kb  = Qb + 6291456;
  unsigned short* Vt  = Kb + 2 * 6291456;
  unsigned short* Ob  = xb;  // xb dead after QKV projection

  cast_x<<<6144, 256, 0, stream>>>(x, xb, 1572864);
  cast_wt4<<<dim3(48, 48, 4), dim3(16, 16), 0, stream>>>(Wq, Wk, Wv, Wo, WtQ, WtK, WtV, WtO);
  gemm_qkv<<<1152, 256, 0, stream>>>(xb, WtQ, bq, bk, bv, Qb, Kb, Vt);
  attn<<<768, 256, 0, stream>>>(Qb, Kb, Vt, Ob);
  gemm_out<<<384, 256, 0, stream>>>(Ob, WtO, bo, out);
}